// Round 7
// baseline (236.470 us; speedup 1.0000x reference)
//
#include <hip/hip_runtime.h>

// region_pooling via scatter + dense GEMM + split-k partials.
// F: [B=8, HW=4096, C=1024] fp32 (H=W=64); pc: [B, M=32, P=512, 2]
// out[b,m,c] = sum_hw W[b][hw][m] * F[b][hw][c]; W = scattered bilinear
// weights pre-scaled by 1/P.
//
// v7: no k-loop barriers at all. W chunk staged to LDS once (1 barrier),
// read as wave-uniform broadcasts; F streamed global->register through an
// unconditional 8-deep ring (compile-time indices, no guard -> compiler
// keeps the pipeline). CPT=4 halves acc pressure: ~90 VGPR, grid 1024
// blocks = 4 blk/CU = 16 waves/CU (2x v6 occupancy).

#define NB 8
#define NM 32
#define NP 512
#define NC 1024
#define NH 64
#define NHW 4096

#define KC    128                 // hw per k-chunk
#define NKC   (NHW / KC)          // 32 k-chunks
#define MT    8                   // m's per wave (4 waves = all 32 m)
#define CTILE 256                 // channels per block (lane owns 4)
#define NCT   (NC / CTILE)        // 4 c-tiles
#define PF    8                   // F ring depth (steps)
#define FS4   (NC / 4)            // float4 stride per hw row

// ---- Phase 1: scatter bilinear weights into W[b][hw][m] (pre-zeroed) ----
__global__ __launch_bounds__(256) void scatter_w(
    const float* __restrict__ pc, float* __restrict__ W)
{
    int idx = blockIdx.x * 256 + threadIdx.x;   // [0, B*M*P)
    int bm  = idx >> 9;                         // b*NM + m
    int m   = bm & (NM - 1);
    int b   = bm >> 5;

    float2 c = ((const float2*)pc)[idx];
    float y = c.x * 63.0f;
    float x = c.y * 63.0f;
    float x0f = floorf(x), y0f = floorf(y);
    float wx = x - x0f, wy = y - y0f;
    int ix0 = min(max((int)x0f, 0), 63);
    int ix1 = min(ix0 + 1, 63);
    int iy0 = min(max((int)y0f, 0), 63);
    int iy1 = min(iy0 + 1, 63);
    float wx1 = 1.0f - wx, wy1 = 1.0f - wy;
    const float s = 1.0f / (float)NP;           // fold the mean here

    float* Wb = W + (size_t)b * (NHW * NM) + m;
    atomicAdd(Wb + ((iy0 * NH + ix0) * NM), wx1 * wy1 * s);
    atomicAdd(Wb + ((iy0 * NH + ix1) * NM), wx  * wy1 * s);
    atomicAdd(Wb + ((iy1 * NH + ix0) * NM), wx1 * wy  * s);
    atomicAdd(Wb + ((iy1 * NH + ix1) * NM), wx  * wy  * s);
}

// ---- Phase 2: P[kc][b][m][c] = sum_{hw in chunk kc} W[b][hw][m]*F[b][hw][c]
// Grid (NKC, NCT, NB) = (32, 4, 8) = 1024 blocks, 256 thr = 4 waves;
// 4 blocks/CU = 16 waves/CU. Wave mq owns m-octet [mq*8, mq*8+8); lane owns
// channels [ct*256 + 4*lane, +4). No barriers in the k-loop.
__global__ __launch_bounds__(256, 4) void wgemm(
    const float* __restrict__ W, const float* __restrict__ F,
    float* __restrict__ P)
{
    __shared__ float sW[KC * NM];               // 16 KB

    const int kc   = blockIdx.x;
    const int ct   = blockIdx.y;
    const int b    = blockIdx.z;
    const int tid  = threadIdx.x;
    const int mq   = tid >> 6;                  // wave id = m-octet
    const int lane = tid & 63;
    const int hw0  = kc * KC;

    // stage W[hw0:hw0+KC][0:32] -> LDS (1024 float4, 4 per thread)
    {
        const float4* Wg = (const float4*)(W + ((size_t)b * NHW + hw0) * NM);
        float4* sW4 = (float4*)sW;
#pragma unroll
        for (int j = 0; j < 4; ++j)
            sW4[tid + 256 * j] = Wg[tid + 256 * j];
    }
    __syncthreads();                            // the only barrier

    const float4* __restrict__ Fb =
        (const float4*)(F + ((size_t)b * NHW + hw0) * NC + ct * CTILE) + lane;

    float4 acc[MT];
#pragma unroll
    for (int m = 0; m < MT; ++m) acc[m] = make_float4(0.f, 0.f, 0.f, 0.f);

    // unconditional 8-deep F ring (indices compile-time after unroll)
    float4 r[PF];
#pragma unroll
    for (int j = 0; j < PF; ++j) r[j] = Fb[j * FS4];

    const float* sWq = sW + mq * MT;            // row stride NM

    for (int t = 0; t < KC - PF; t += PF) {
#pragma unroll
        for (int j = 0; j < PF; ++j) {
            float4 f = r[j];
            r[j] = Fb[(t + j + PF) * FS4];      // unconditional prefetch
            const float* wr = sWq + (t + j) * NM;
            float4 w0 = *(const float4*)(wr);       // broadcast ds_read
            float4 w1 = *(const float4*)(wr + 4);
            const float wm[MT] = { w0.x, w0.y, w0.z, w0.w,
                                   w1.x, w1.y, w1.z, w1.w };
#pragma unroll
            for (int m = 0; m < MT; ++m) {
                float w = wm[m];
                acc[m].x = fmaf(w, f.x, acc[m].x);
                acc[m].y = fmaf(w, f.y, acc[m].y);
                acc[m].z = fmaf(w, f.z, acc[m].z);
                acc[m].w = fmaf(w, f.w, acc[m].w);
            }
        }
    }
    // tail: consume the last PF ring slots (steps KC-PF .. KC-1)
#pragma unroll
    for (int j = 0; j < PF; ++j) {
        float4 f = r[j];
        const float* wr = sWq + (KC - PF + j) * NM;
        float4 w0 = *(const float4*)(wr);
        float4 w1 = *(const float4*)(wr + 4);
        const float wm[MT] = { w0.x, w0.y, w0.z, w0.w,
                               w1.x, w1.y, w1.z, w1.w };
#pragma unroll
        for (int m = 0; m < MT; ++m) {
            float w = wm[m];
            acc[m].x = fmaf(w, f.x, acc[m].x);
            acc[m].y = fmaf(w, f.y, acc[m].y);
            acc[m].z = fmaf(w, f.z, acc[m].z);
            acc[m].w = fmaf(w, f.w, acc[m].w);
        }
    }

    // partials: P[((kc*NB + b)*NM + m)*NC + c]; coalesced float4 stores
    float* pb = P + (((size_t)kc * NB + b) * NM + mq * MT) * NC
              + ct * CTILE + 4 * lane;
#pragma unroll
    for (int mm = 0; mm < MT; ++mm)
        *(float4*)(pb + (size_t)mm * NC) = acc[mm];
}

// ---- Phase 3: out = sum over the 32 k-chunk partials ----
__global__ __launch_bounds__(256) void reduce_p(
    const float* __restrict__ P, float* __restrict__ out)
{
    const int idx = blockIdx.x * 256 + threadIdx.x;   // [0, NB*NM*NC/4)
    const float4* p4 = (const float4*)P;
    const int stride = NB * NM * NC / 4;              // 65536
    float4 s = make_float4(0.f, 0.f, 0.f, 0.f);
#pragma unroll
    for (int kc = 0; kc < NKC; ++kc) {
        float4 v = p4[(size_t)kc * stride + idx];
        s.x += v.x; s.y += v.y; s.z += v.z; s.w += v.w;
    }
    ((float4*)out)[idx] = s;
}

// ---- Fallback (ws too small): direct gather ----
__global__ __launch_bounds__(256) void region_pool_direct(
    const float* __restrict__ fm, const float* __restrict__ pc,
    float* __restrict__ out)
{
    __shared__ int4   sIdx[NP];
    __shared__ float4 sWt[NP];
    const int bid = blockIdx.x;
    const int b   = bid >> 5;
    const int tid = threadIdx.x;
    const float2* pc2 = (const float2*)(pc + (size_t)bid * NP * 2);
    for (int p = tid; p < NP; p += 256) {
        float2 c = pc2[p];
        float y = c.x * 63.0f, x = c.y * 63.0f;
        float x0f = floorf(x), y0f = floorf(y);
        float wx = x - x0f, wy = y - y0f;
        int ix0 = min(max((int)x0f, 0), 63);
        int ix1 = min(ix0 + 1, 63);
        int iy0 = min(max((int)y0f, 0), 63);
        int iy1 = min(iy0 + 1, 63);
        sIdx[p] = make_int4((iy0 * NH + ix0) << 10, (iy0 * NH + ix1) << 10,
                            (iy1 * NH + ix0) << 10, (iy1 * NH + ix1) << 10);
        float wx1 = 1.0f - wx, wy1 = 1.0f - wy;
        sWt[p] = make_float4(wx1 * wy1, wx * wy1, wx1 * wy, wx * wy);
    }
    __syncthreads();
    const float* Fb = fm + (size_t)b * (NHW * NC) + tid * 4;
    float4 acc = make_float4(0.f, 0.f, 0.f, 0.f);
#pragma unroll 4
    for (int p = 0; p < NP; ++p) {
        int4 off = sIdx[p]; float4 w = sWt[p];
        float4 f00 = *(const float4*)(Fb + off.x);
        float4 f01 = *(const float4*)(Fb + off.y);
        float4 f10 = *(const float4*)(Fb + off.z);
        float4 f11 = *(const float4*)(Fb + off.w);
        acc.x = fmaf(w.x, f00.x, fmaf(w.y, f01.x, fmaf(w.z, f10.x, fmaf(w.w, f11.x, acc.x))));
        acc.y = fmaf(w.x, f00.y, fmaf(w.y, f01.y, fmaf(w.z, f10.y, fmaf(w.w, f11.y, acc.y))));
        acc.z = fmaf(w.x, f00.z, fmaf(w.y, f01.z, fmaf(w.z, f10.z, fmaf(w.w, f11.z, acc.z))));
        acc.w = fmaf(w.x, f00.w, fmaf(w.y, f01.w, fmaf(w.z, f10.w, fmaf(w.w, f11.w, acc.w))));
    }
    const float inv = 1.0f / (float)NP;
    ((float4*)(out + (size_t)bid * NC))[tid] =
        make_float4(acc.x * inv, acc.y * inv, acc.z * inv, acc.w * inv);
}

extern "C" void kernel_launch(void* const* d_in, const int* in_sizes, int n_in,
                              void* d_out, int out_size, void* d_ws, size_t ws_size,
                              hipStream_t stream) {
    const float* fm = (const float*)d_in[0];   // [8, 4096, 1024]
    const float* pc = (const float*)d_in[1];   // [8, 32, 512, 2]
    float* out = (float*)d_out;                // [8, 32, 1, 1024]

    const size_t wbytes = (size_t)NB * NHW * NM * sizeof(float);           // 4 MB
    const size_t pbytes = (size_t)NKC * NB * NM * NC * sizeof(float);      // 32 MB
    if (ws_size >= wbytes + pbytes) {
        float* W = (float*)d_ws;
        float* P = (float*)((char*)d_ws + wbytes);
        hipMemsetAsync(W, 0, wbytes, stream);
        scatter_w<<<(NB * NM * NP) / 256, 256, 0, stream>>>(pc, W);
        dim3 grid(NKC, NCT, NB);
        wgemm<<<grid, 256, 0, stream>>>(W, fm, P);
        reduce_p<<<(NB * NM * NC / 4) / 256, 256, 0, stream>>>(P, out);
    } else {
        region_pool_direct<<<NB * NM, 256, 0, stream>>>(fm, pc, out);
    }
}

// Round 8
// 233.995 us; speedup vs baseline: 1.0106x; 1.0106x over previous
//
#include <hip/hip_runtime.h>

// region_pooling via scatter + dense GEMM + split-k partials.
// F: [B=8, HW=4096, C=1024] fp32 (H=W=64); pc: [B, M=32, P=512, 2]
// out[b,m,c] = sum_hw W[b][hw][m] * F[b][hw][c]; W = scattered bilinear
// weights pre-scaled by 1/P.
//
// v8: k-loop restructured into 16-step register-double-buffered segments.
// All 16 next-segment F loads issued as one batch, then 16 steps (1024 VALU
// cyc) compute on the current buffer -> even a worst-case vmcnt(0) at the
// swap exposes zero latency. Named bufA/bufB + fully unrolled segment loop
// keep every index compile-time. W read as wave-uniform ds_read_b128 with
// immediate offsets. ~180 VGPR, 2 waves/SIMD.

#define NB 8
#define NM 32
#define NP 512
#define NC 1024
#define NH 64
#define NHW 4096

#define KC    128                 // hw per k-chunk
#define NKC   (NHW / KC)          // 32 k-chunks
#define MT    8                   // m's per wave (4 waves = all 32 m)
#define CTILE 256                 // channels per block (lane owns 4)
#define NCT   (NC / CTILE)        // 4 c-tiles
#define SEG   16                  // steps per segment
#define NSEG  (KC / SEG)          // 8 segments
#define FS4   (NC / 4)            // float4 stride per hw row

// ---- Phase 1: scatter bilinear weights into W[b][hw][m] (pre-zeroed) ----
__global__ __launch_bounds__(256) void scatter_w(
    const float* __restrict__ pc, float* __restrict__ W)
{
    int idx = blockIdx.x * 256 + threadIdx.x;   // [0, B*M*P)
    int bm  = idx >> 9;                         // b*NM + m
    int m   = bm & (NM - 1);
    int b   = bm >> 5;

    float2 c = ((const float2*)pc)[idx];
    float y = c.x * 63.0f;
    float x = c.y * 63.0f;
    float x0f = floorf(x), y0f = floorf(y);
    float wx = x - x0f, wy = y - y0f;
    int ix0 = min(max((int)x0f, 0), 63);
    int ix1 = min(ix0 + 1, 63);
    int iy0 = min(max((int)y0f, 0), 63);
    int iy1 = min(iy0 + 1, 63);
    float wx1 = 1.0f - wx, wy1 = 1.0f - wy;
    const float s = 1.0f / (float)NP;           // fold the mean here

    float* Wb = W + (size_t)b * (NHW * NM) + m;
    atomicAdd(Wb + ((iy0 * NH + ix0) * NM), wx1 * wy1 * s);
    atomicAdd(Wb + ((iy0 * NH + ix1) * NM), wx  * wy1 * s);
    atomicAdd(Wb + ((iy1 * NH + ix0) * NM), wx1 * wy  * s);
    atomicAdd(Wb + ((iy1 * NH + ix1) * NM), wx  * wy  * s);
}

// ---- Phase 2: P[kc][b][m][c] = sum_{hw in chunk kc} W[b][hw][m]*F[b][hw][c]
// Grid (NKC, NCT, NB) = (32, 4, 8) = 1024 blocks, 256 thr = 4 waves.
// Wave mq owns m-octet [mq*8, mq*8+8); lane owns channels ct*256+4*lane..+4.
__global__ __launch_bounds__(256, 2) void wgemm(
    const float* __restrict__ W, const float* __restrict__ F,
    float* __restrict__ P)
{
    __shared__ float sW[KC * NM];               // 16 KB

    const int kc   = blockIdx.x;
    const int ct   = blockIdx.y;
    const int b    = blockIdx.z;
    const int tid  = threadIdx.x;
    const int mq   = tid >> 6;                  // wave id = m-octet
    const int lane = tid & 63;
    const int hw0  = kc * KC;

    // stage W[hw0:hw0+KC][0:32] -> LDS (1024 float4, 4 per thread)
    {
        const float4* Wg = (const float4*)(W + ((size_t)b * NHW + hw0) * NM);
        float4* sW4 = (float4*)sW;
#pragma unroll
        for (int j = 0; j < 4; ++j)
            sW4[tid + 256 * j] = Wg[tid + 256 * j];
    }
    __syncthreads();                            // the only barrier

    const float4* __restrict__ Fb =
        (const float4*)(F + ((size_t)b * NHW + hw0) * NC + ct * CTILE) + lane;

    float4 acc[MT];
#pragma unroll
    for (int m = 0; m < MT; ++m) acc[m] = make_float4(0.f, 0.f, 0.f, 0.f);

    const float* sWq = sW + mq * MT;            // row stride NM floats

    // one FMA step on row (compile-time) r with f already in registers
#define STEP(r, fv)                                                        \
    do {                                                                   \
        const float* wr_ = sWq + (r) * NM;                                 \
        float4 w0_ = *(const float4*)(wr_);                                \
        float4 w1_ = *(const float4*)(wr_ + 4);                            \
        const float wm_[MT] = { w0_.x, w0_.y, w0_.z, w0_.w,                \
                                w1_.x, w1_.y, w1_.z, w1_.w };              \
        _Pragma("unroll")                                                  \
        for (int m_ = 0; m_ < MT; ++m_) {                                  \
            float w_ = wm_[m_];                                            \
            acc[m_].x = fmaf(w_, (fv).x, acc[m_].x);                       \
            acc[m_].y = fmaf(w_, (fv).y, acc[m_].y);                       \
            acc[m_].z = fmaf(w_, (fv).z, acc[m_].z);                       \
            acc[m_].w = fmaf(w_, (fv).w, acc[m_].w);                       \
        }                                                                  \
    } while (0)

    float4 bufA[SEG], bufB[SEG];

    // prologue: segment 0 -> bufA
#pragma unroll
    for (int j = 0; j < SEG; ++j) bufA[j] = Fb[j * FS4];

#pragma unroll
    for (int s = 0; s < NSEG; s += 2) {
        // prefetch segment s+1 -> bufB (batch of 16 loads)
        if (s + 1 < NSEG) {
#pragma unroll
            for (int j = 0; j < SEG; ++j)
                bufB[j] = Fb[((s + 1) * SEG + j) * FS4];
        }
        // compute segment s from bufA (1024 VALU cyc)
#pragma unroll
        for (int j = 0; j < SEG; ++j) STEP(s * SEG + j, bufA[j]);

        // prefetch segment s+2 -> bufA
        if (s + 2 < NSEG) {
#pragma unroll
            for (int j = 0; j < SEG; ++j)
                bufA[j] = Fb[((s + 2) * SEG + j) * FS4];
        }
        // compute segment s+1 from bufB
        if (s + 1 < NSEG) {
#pragma unroll
            for (int j = 0; j < SEG; ++j) STEP((s + 1) * SEG + j, bufB[j]);
        }
    }
#undef STEP

    // partials: P[((kc*NB + b)*NM + m)*NC + c]; coalesced float4 stores
    float* pb = P + (((size_t)kc * NB + b) * NM + mq * MT) * NC
              + ct * CTILE + 4 * lane;
#pragma unroll
    for (int mm = 0; mm < MT; ++mm)
        *(float4*)(pb + (size_t)mm * NC) = acc[mm];
}

// ---- Phase 3: out = sum over the 32 k-chunk partials ----
__global__ __launch_bounds__(256) void reduce_p(
    const float* __restrict__ P, float* __restrict__ out)
{
    const int idx = blockIdx.x * 256 + threadIdx.x;   // [0, NB*NM*NC/4)
    const float4* p4 = (const float4*)P;
    const int stride = NB * NM * NC / 4;              // 65536
    float4 s = make_float4(0.f, 0.f, 0.f, 0.f);
#pragma unroll
    for (int kc = 0; kc < NKC; ++kc) {
        float4 v = p4[(size_t)kc * stride + idx];
        s.x += v.x; s.y += v.y; s.z += v.z; s.w += v.w;
    }
    ((float4*)out)[idx] = s;
}

// ---- Fallback (ws too small): direct gather ----
__global__ __launch_bounds__(256) void region_pool_direct(
    const float* __restrict__ fm, const float* __restrict__ pc,
    float* __restrict__ out)
{
    __shared__ int4   sIdx[NP];
    __shared__ float4 sWt[NP];
    const int bid = blockIdx.x;
    const int b   = bid >> 5;
    const int tid = threadIdx.x;
    const float2* pc2 = (const float2*)(pc + (size_t)bid * NP * 2);
    for (int p = tid; p < NP; p += 256) {
        float2 c = pc2[p];
        float y = c.x * 63.0f, x = c.y * 63.0f;
        float x0f = floorf(x), y0f = floorf(y);
        float wx = x - x0f, wy = y - y0f;
        int ix0 = min(max((int)x0f, 0), 63);
        int ix1 = min(ix0 + 1, 63);
        int iy0 = min(max((int)y0f, 0), 63);
        int iy1 = min(iy0 + 1, 63);
        sIdx[p] = make_int4((iy0 * NH + ix0) << 10, (iy0 * NH + ix1) << 10,
                            (iy1 * NH + ix0) << 10, (iy1 * NH + ix1) << 10);
        float wx1 = 1.0f - wx, wy1 = 1.0f - wy;
        sWt[p] = make_float4(wx1 * wy1, wx * wy1, wx1 * wy, wx * wy);
    }
    __syncthreads();
    const float* Fb = fm + (size_t)b * (NHW * NC) + tid * 4;
    float4 acc = make_float4(0.f, 0.f, 0.f, 0.f);
#pragma unroll 4
    for (int p = 0; p < NP; ++p) {
        int4 off = sIdx[p]; float4 w = sWt[p];
        float4 f00 = *(const float4*)(Fb + off.x);
        float4 f01 = *(const float4*)(Fb + off.y);
        float4 f10 = *(const float4*)(Fb + off.z);
        float4 f11 = *(const float4*)(Fb + off.w);
        acc.x = fmaf(w.x, f00.x, fmaf(w.y, f01.x, fmaf(w.z, f10.x, fmaf(w.w, f11.x, acc.x))));
        acc.y = fmaf(w.x, f00.y, fmaf(w.y, f01.y, fmaf(w.z, f10.y, fmaf(w.w, f11.y, acc.y))));
        acc.z = fmaf(w.x, f00.z, fmaf(w.y, f01.z, fmaf(w.z, f10.z, fmaf(w.w, f11.z, acc.z))));
        acc.w = fmaf(w.x, f00.w, fmaf(w.y, f01.w, fmaf(w.z, f10.w, fmaf(w.w, f11.w, acc.w))));
    }
    const float inv = 1.0f / (float)NP;
    ((float4*)(out + (size_t)bid * NC))[tid] =
        make_float4(acc.x * inv, acc.y * inv, acc.z * inv, acc.w * inv);
}

extern "C" void kernel_launch(void* const* d_in, const int* in_sizes, int n_in,
                              void* d_out, int out_size, void* d_ws, size_t ws_size,
                              hipStream_t stream) {
    const float* fm = (const float*)d_in[0];   // [8, 4096, 1024]
    const float* pc = (const float*)d_in[1];   // [8, 32, 512, 2]
    float* out = (float*)d_out;                // [8, 32, 1, 1024]

    const size_t wbytes = (size_t)NB * NHW * NM * sizeof(float);           // 4 MB
    const size_t pbytes = (size_t)NKC * NB * NM * NC * sizeof(float);      // 32 MB
    if (ws_size >= wbytes + pbytes) {
        float* W = (float*)d_ws;
        float* P = (float*)((char*)d_ws + wbytes);
        hipMemsetAsync(W, 0, wbytes, stream);
        scatter_w<<<(NB * NM * NP) / 256, 256, 0, stream>>>(pc, W);
        dim3 grid(NKC, NCT, NB);
        wgemm<<<grid, 256, 0, stream>>>(W, fm, P);
        reduce_p<<<(NB * NM * NC / 4) / 256, 256, 0, stream>>>(P, out);
    } else {
        region_pool_direct<<<NB * NM, 256, 0, stream>>>(fm, pc, out);
    }
}